// Round 6
// baseline (110.618 us; speedup 1.0000x reference)
//
#include <hip/hip_runtime.h>
#include <math.h>

constexpr int Bv   = 8;
constexpr int Nv   = 2048;
constexpr int FIN  = 128;
constexpr int FOUT = 128;
constexpr int NH   = 2;
constexpr float LOG2E = 1.44269504088896340736f;

typedef __attribute__((ext_vector_type(8)))  short short8;
typedef __attribute__((ext_vector_type(4)))  float f32x4;
typedef __attribute__((ext_vector_type(16))) float f32x16;
typedef __attribute__((ext_vector_type(4)))  int   i32x4;
typedef unsigned long long u64;

static __device__ __forceinline__ unsigned short f2bf(float f) {
    unsigned u = __builtin_bit_cast(unsigned, f);
    u += 0x7fffu + ((u >> 16) & 1u);          // round-to-nearest-even
    return (unsigned short)(u >> 16);
}
static __device__ __forceinline__ float bf2f(unsigned short s) {
    unsigned u = ((unsigned)s) << 16;
    return __builtin_bit_cast(float, u);
}
static __device__ __forceinline__ float fast_exp2(float x) {
#if __has_builtin(__builtin_amdgcn_exp2f)
    return __builtin_amdgcn_exp2f(x);
#else
    return exp2f(x);
#endif
}
static __device__ __forceinline__ unsigned cvt_pk_bf16(float lo, float hi) {
    unsigned r;
    asm("v_cvt_pk_bf16_f32 %0, %1, %2" : "=v"(r) : "v"(lo), "v"(hi));
    return r;
}

// ---------------- Kernel 0: wa (log2 domain) + W transpose/bf16-split ----------------
// grid 2 (one per head). Also writes Wt[hh][o][f] hi/lo bf16 (coalesced via LDS transpose)
// so the prep kernel needs ZERO LDS (occupancy unlock).
__global__ __launch_bounds__(256) void wa_kernel(const float* __restrict__ W,
                                                 const float* __restrict__ a,
                                                 float* __restrict__ wa,
                                                 unsigned short* __restrict__ wthi,
                                                 unsigned short* __restrict__ wtlo) {
    __shared__ unsigned short shi[FIN * 132];
    __shared__ unsigned short slo[FIN * 132];
    int hh = blockIdx.x;
    int t = threadIdx.x;

    const float* Ws = W + (size_t)hh * FIN * FOUT;
    for (int idx = t; idx < FIN * FOUT; idx += 256) {
        int f = idx >> 7, o = idx & 127;
        float wv = Ws[idx];
        unsigned short uh = f2bf(wv);
        shi[o * 132 + f] = uh;
        slo[o * 132 + f] = f2bf(wv - bf2f(uh));
    }

    // wa[h][q][f] = log2e * sum_o W[h][f][o] * a[h][q*FOUT+o]
    int f = t >> 1, half = t & 1;
    const float* Wr = Ws + (size_t)f * FOUT + half * 64;
    const float* ar = a + (size_t)hh * 2 * FOUT + half * 64;
    float s1 = 0.f, s2 = 0.f;
    for (int o = 0; o < 64; o += 4) {
        float4 w4 = *(const float4*)&Wr[o];
        s1 += w4.x * ar[o] + w4.y * ar[o + 1] + w4.z * ar[o + 2] + w4.w * ar[o + 3];
        s2 += w4.x * ar[FOUT + o] + w4.y * ar[FOUT + o + 1] + w4.z * ar[FOUT + o + 2] + w4.w * ar[FOUT + o + 3];
    }
    s1 += __shfl_xor(s1, 1, 64);
    s2 += __shfl_xor(s2, 1, 64);
    if (half == 0) {
        wa[(hh * 2 + 0) * FIN + f] = s1 * LOG2E;
        wa[(hh * 2 + 1) * FIN + f] = s2 * LOG2E;
    }

    __syncthreads();
    // coalesced transposed write-out
    unsigned short* dhi = wthi + (size_t)hh * FOUT * FIN;
    unsigned short* dlo = wtlo + (size_t)hh * FOUT * FIN;
    for (int idx = t; idx < FIN * FOUT; idx += 256) {
        int o = idx >> 7, ff = idx & 127;
        dhi[idx] = shi[o * 132 + ff];
        dlo[idx] = slo[o * 132 + ff];
    }
}

// ---------------- Fat prep kernel (LDS-free): pack | sij | wh ----------------
// whf layout (per b,h): chunk = (jt*4 + kt)*4 + ctq; elem (col o, row n):
//   jt=n>>6, kt=(n>>4)&3, kh=(n>>3)&1, i=n&7, ctq=o>>5; flat = (chunk*64 + kh*32 + (o&31))*8 + i
__global__ __launch_bounds__(256, 4) void prep_kernel(
    const float* __restrict__ h, const int* __restrict__ adj,
    const float* __restrict__ wa,
    const unsigned short* __restrict__ wthi, const unsigned short* __restrict__ wtlo,
    u64* __restrict__ adjp, unsigned short* __restrict__ whf,
    float* __restrict__ si, float* __restrict__ sj) {
    int bid = blockIdx.x;
    int t   = threadIdx.x;

    if (bid < 4096) {
        // ---------------- pack: adjp[b][jt][n] = bitmask of 64 j's ----------------
        int wid = bid * 4 + (t >> 6);
        int l   = t & 63;
        int b   = wid >> 11;
        int r5  = wid & 2047;
        int jt  = r5 >> 6;
        int rb  = r5 & 63;
        const int* src = adj + ((size_t)b * Nv + rb * 32) * Nv + jt * 64 + l;
        u64* dst = adjp + ((size_t)b * 32 + jt) * Nv + rb * 32;
        for (int r = 0; r < 32; r += 8) {
            int av[8];
#pragma unroll
            for (int k = 0; k < 8; ++k) av[k] = src[(size_t)(r + k) * Nv];
            u64 m[8];
#pragma unroll
            for (int k = 0; k < 8; ++k) m[k] = __ballot(av[k] != 0);
            if (l == 0) {
#pragma unroll
                for (int k = 0; k < 8; k += 2) {
                    uint4 q = {(unsigned)m[k], (unsigned)(m[k] >> 32),
                               (unsigned)m[k + 1], (unsigned)(m[k + 1] >> 32)};
                    *(uint4*)&dst[r + k] = q;
                }
            }
        }
    } else if (bid < 8192) {
        // ---------------- sij ----------------
        int row  = (bid - 4096) * 4 + (t >> 6);
        int lane = t & 63;
        float x0 = h[(size_t)row * FIN + lane];
        float x1 = h[(size_t)row * FIN + 64 + lane];
        float s[4];
#pragma unroll
        for (int q = 0; q < 4; ++q) {
            const float* wp = wa + q * FIN;
            s[q] = x0 * wp[lane] + x1 * wp[64 + lane];
        }
#pragma unroll
        for (int m = 32; m >= 1; m >>= 1) {
#pragma unroll
            for (int q = 0; q < 4; ++q) s[q] += __shfl_xor(s[q], m, 64);
        }
        if (lane == 0) {
            int bb = row >> 11, n = row & (Nv - 1);
            si[((size_t)(bb * NH + 0)) * Nv + n] = s[0];
            sj[((size_t)(bb * NH + 0)) * Nv + n] = s[1];
            si[((size_t)(bb * NH + 1)) * Nv + n] = s[2];
            sj[((size_t)(bb * NH + 1)) * Nv + n] = s[3];
        }
    } else {
        // ---------------- wh: Wh bf16 (hi/lo split, fp32-accurate) into frag-major whf ----------
        int wb2 = bid - 8192;          // 0..511
        int bb  = wb2 & 7;
        int r2  = wb2 >> 3;
        int hh  = r2 & 1;
        int jtb = r2 >> 1;             // 64-row tile index
        int n0  = jtb * 64;

        int w = t >> 6, l = t & 63, lo16 = l & 15, grp = l >> 4;
        int o0 = w * 32;

        const unsigned short* Whi = wthi + (size_t)hh * FOUT * FIN;
        const unsigned short* Wlo = wtlo + (size_t)hh * FOUT * FIN;
        short8 ahi[2][4], alo[2][4];
#pragma unroll
        for (int ot = 0; ot < 2; ++ot)
#pragma unroll
            for (int kt = 0; kt < 4; ++kt) {
                int off = (o0 + ot * 16 + lo16) * FIN + kt * 32 + grp * 8;
                ahi[ot][kt] = *(const short8*)&Whi[off];
                alo[ot][kt] = *(const short8*)&Wlo[off];
            }

        f32x4 acc[2][4];
#pragma unroll
        for (int ot = 0; ot < 2; ++ot)
#pragma unroll
            for (int nt = 0; nt < 4; ++nt) acc[ot][nt] = (f32x4){0.f, 0.f, 0.f, 0.f};

        const float* hb = h + ((size_t)bb * Nv + n0) * FIN;
#pragma unroll
        for (int nt = 0; nt < 4; ++nt) {
#pragma unroll
            for (int kt = 0; kt < 4; ++kt) {
                const float* hp = hb + (size_t)(nt * 16 + lo16) * FIN + kt * 32 + grp * 8;
                float4 x0 = *(const float4*)hp;
                float4 x1 = *(const float4*)(hp + 4);
                float xs[8] = {x0.x, x0.y, x0.z, x0.w, x1.x, x1.y, x1.z, x1.w};
                short8 bhi, blo;
#pragma unroll
                for (int i = 0; i < 8; ++i) {
                    unsigned short uh = f2bf(xs[i]);
                    bhi[i] = (short)uh;
                    blo[i] = (short)f2bf(xs[i] - bf2f(uh));
                }
#pragma unroll
                for (int ot = 0; ot < 2; ++ot) {
                    acc[ot][nt] = __builtin_amdgcn_mfma_f32_16x16x32_bf16(ahi[ot][kt], bhi, acc[ot][nt], 0, 0, 0);
                    acc[ot][nt] = __builtin_amdgcn_mfma_f32_16x16x32_bf16(ahi[ot][kt], blo, acc[ot][nt], 0, 0, 0);
                    acc[ot][nt] = __builtin_amdgcn_mfma_f32_16x16x32_bf16(alo[ot][kt], bhi, acc[ot][nt], 0, 0, 0);
                }
            }
        }
        unsigned short* db = whf + (size_t)(bb * NH + hh) * 262144;
#pragma unroll
        for (int ot = 0; ot < 2; ++ot)
#pragma unroll
            for (int nt = 0; nt < 4; ++nt)
#pragma unroll
                for (int reg = 0; reg < 4; ++reg) {
                    int oc = ot * 16 + grp * 4 + reg;
                    db[(size_t)(((jtb * 4 + nt) * 4 + w) * 64 + (lo16 >> 3) * 32 + oc) * 8 + (lo16 & 7)] =
                        f2bf(acc[ot][nt][reg]);
                }
    }
}

// ---------------- attn: 32x32x16 MFMA, j-split x2, no online max, bitmask adj ----------------
// grid 1024: bb=bid&7 (XCD), rp=(bid>>3)&31 (64-row pair), hh=(bid>>8)&1, ch=bid>>9 (col half).
// 4 waves: jp=w&1 (j-half, 16 tiles each), rw=w>>1 (32-row group). Wave: 32 rows x 64 cols.
// A layout (32x32x16): row=l&31, k=(l>>5)*8+i. C/D: col=l&31, row=(reg&3)+8*(reg>>2)+4*(l>>5).
__global__ __launch_bounds__(256, 3) void gat_attn_kernel(
    const u64* __restrict__ adjp, const unsigned short* __restrict__ whf,
    const float* __restrict__ si, const float* __restrict__ sj,
    float* __restrict__ out) {
    int bid = blockIdx.x;
    int bb  = bid & 7;
    int r2  = bid >> 3;
    int rp  = r2 & 31;
    int hh  = (r2 >> 5) & 1;
    int ch  = r2 >> 6;

    int t = threadIdx.x, w = t >> 6, l = t & 63;
    int jp = w & 1, rw = w >> 1;
    int lo32 = l & 31, kh = l >> 5;
    int r0 = rp * 64 + rw * 32;
    int myrow = r0 + lo32;

    float sir = si[(size_t)(bb * NH + hh) * Nv + myrow];
    const u64*   adjr = adjp + (size_t)bb * 32 * Nv + myrow;
    const float* sjb  = sj + (size_t)(bb * NH + hh) * Nv;
    const unsigned short* wbp = whf + (size_t)(bb * NH + hh) * 262144 + (size_t)l * 8;

    f32x16 acc0, acc1, accL;
#pragma unroll
    for (int i = 0; i < 16; ++i) { acc0[i] = 0.f; acc1[i] = 0.f; accL[i] = 0.f; }

    const int ones_w = 0x3f803f80;
    short8 onesf = __builtin_bit_cast(short8, (i32x4){ones_w, ones_w, ones_w, ones_w});

    int jt0 = jp * 16;
    u64 mask = adjr[(size_t)jt0 * Nv];
    for (int jtl = 0; jtl < 16; ++jtl) {
        int jt = jt0 + jtl;
        int jb = jt * 64;
        const unsigned short* fb = wbp + (size_t)(jt * 16 + ch * 2) * 512;
        short8 bf[4][2];
#pragma unroll
        for (int kt = 0; kt < 4; ++kt) {
            bf[kt][0] = *(const short8*)(fb + (kt * 4 + 0) * 512);
            bf[kt][1] = *(const short8*)(fb + (kt * 4 + 1) * 512);
        }
        u64 mcur = mask;
        if (jtl < 15) mask = adjr[(size_t)(jt + 1) * Nv];

        short8 af[4];
#pragma unroll
        for (int kt = 0; kt < 4; ++kt) {
            unsigned mb = (unsigned)(mcur >> (kt * 16 + kh * 8)) & 0xFFu;
            const float* sp = &sjb[jb + kt * 16 + kh * 8];
            float4 s0 = *(const float4*)sp;
            float4 s1 = *(const float4*)(sp + 4);
            float x0 = sir + s0.x, x1 = sir + s0.y, x2 = sir + s0.z, x3 = sir + s0.w;
            float x4 = sir + s1.x, x5 = sir + s1.y, x6 = sir + s1.z, x7 = sir + s1.w;
            x0 = fmaxf(x0, 0.2f * x0); x1 = fmaxf(x1, 0.2f * x1);
            x2 = fmaxf(x2, 0.2f * x2); x3 = fmaxf(x3, 0.2f * x3);
            x4 = fmaxf(x4, 0.2f * x4); x5 = fmaxf(x5, 0.2f * x5);
            x6 = fmaxf(x6, 0.2f * x6); x7 = fmaxf(x7, 0.2f * x7);
            float p0 = fast_exp2(x0), p1 = fast_exp2(x1), p2 = fast_exp2(x2), p3 = fast_exp2(x3);
            float p4 = fast_exp2(x4), p5 = fast_exp2(x5), p6 = fast_exp2(x6), p7 = fast_exp2(x7);
            p0 = (mb & 1u)   ? p0 : 0.f;  p1 = (mb & 2u)   ? p1 : 0.f;
            p2 = (mb & 4u)   ? p2 : 0.f;  p3 = (mb & 8u)   ? p3 : 0.f;
            p4 = (mb & 16u)  ? p4 : 0.f;  p5 = (mb & 32u)  ? p5 : 0.f;
            p6 = (mb & 64u)  ? p6 : 0.f;  p7 = (mb & 128u) ? p7 : 0.f;
            unsigned w0 = cvt_pk_bf16(p0, p1), w1 = cvt_pk_bf16(p2, p3);
            unsigned w2 = cvt_pk_bf16(p4, p5), w3 = cvt_pk_bf16(p6, p7);
            af[kt] = __builtin_bit_cast(short8, (i32x4){(int)w0, (int)w1, (int)w2, (int)w3});
        }
#pragma unroll
        for (int kt = 0; kt < 4; ++kt) {
            acc0 = __builtin_amdgcn_mfma_f32_32x32x16_bf16(af[kt], bf[kt][0], acc0, 0, 0, 0);
            acc1 = __builtin_amdgcn_mfma_f32_32x32x16_bf16(af[kt], bf[kt][1], acc1, 0, 0, 0);
            accL = __builtin_amdgcn_mfma_f32_32x32x16_bf16(af[kt], onesf,    accL, 0, 0, 0);
        }
    }

    // ---- j-split combine (plain sums) + normalize + store ----
    __shared__ float red[2][64][49];
    if (jp == 1) {
#pragma unroll
        for (int i = 0; i < 16; ++i) {
            red[rw][l][i]      = acc0[i];
            red[rw][l][16 + i] = acc1[i];
            red[rw][l][32 + i] = accL[i];
        }
    }
    __syncthreads();
    if (jp == 0) {
#pragma unroll
        for (int i = 0; i < 16; ++i) {
            acc0[i] += red[rw][l][i];
            acc1[i] += red[rw][l][16 + i];
            accL[i] += red[rw][l][32 + i];
        }
#pragma unroll
        for (int reg = 0; reg < 16; ++reg) {
            int rowc = (reg & 3) + 8 * (reg >> 2) + 4 * kh;
            float linv = 1.0f / accL[reg];
            float* op = out + ((size_t)(bb * Nv + r0 + rowc)) * (NH * FOUT) + hh * FOUT + ch * 64;
            op[lo32]      = acc0[reg] * linv;
            op[32 + lo32] = acc1[reg] * linv;
        }
    }
}

extern "C" void kernel_launch(void* const* d_in, const int* in_sizes, int n_in,
                              void* d_out, int out_size, void* d_ws, size_t ws_size,
                              hipStream_t stream) {
    const float* h   = (const float*)d_in[0];
    const int*   adj = (const int*)d_in[1];
    const float* W   = (const float*)d_in[2];
    const float* a   = (const float*)d_in[3];
    float*       out = (float*)d_out;

    char* ws = (char*)d_ws;
    unsigned short* whf  = (unsigned short*)ws;                  // 8.39 MB
    u64*            adjp = (u64*)(ws + 8388608);                 // 4.19 MB
    float* si = (float*)(ws + 8388608 + 4194304);                // 128 KB
    float* sj = si + (size_t)Bv * NH * Nv;                       // 128 KB
    float* wa = sj + (size_t)Bv * NH * Nv;                       // 2 KB
    unsigned short* wthi = (unsigned short*)(wa + NH * 2 * FIN); // 64 KB
    unsigned short* wtlo = wthi + (size_t)NH * FOUT * FIN;       // 64 KB

    wa_kernel  <<<dim3(2),    dim3(256), 0, stream>>>(W, a, wa, wthi, wtlo);
    prep_kernel<<<dim3(8704), dim3(256), 0, stream>>>(h, adj, wa, wthi, wtlo, adjp, whf, si, sj);
    gat_attn_kernel<<<dim3(1024), dim3(256), 0, stream>>>(adjp, whf, si, sj, out);
}

// Round 7
// 106.120 us; speedup vs baseline: 1.0424x; 1.0424x over previous
//
#include <hip/hip_runtime.h>
#include <math.h>

constexpr int Bv   = 8;
constexpr int Nv   = 2048;
constexpr int FIN  = 128;
constexpr int FOUT = 128;
constexpr int NH   = 2;
constexpr float LOG2E = 1.44269504088896340736f;

typedef __attribute__((ext_vector_type(8)))  short short8;
typedef __attribute__((ext_vector_type(4)))  float f32x4;
typedef __attribute__((ext_vector_type(16))) float f32x16;
typedef __attribute__((ext_vector_type(4)))  int   i32x4;
typedef unsigned long long u64;

static __device__ __forceinline__ unsigned short f2bf(float f) {
    unsigned u = __builtin_bit_cast(unsigned, f);
    u += 0x7fffu + ((u >> 16) & 1u);          // round-to-nearest-even
    return (unsigned short)(u >> 16);
}
static __device__ __forceinline__ float bf2f(unsigned short s) {
    unsigned u = ((unsigned)s) << 16;
    return __builtin_bit_cast(float, u);
}
static __device__ __forceinline__ float fast_exp2(float x) {
#if __has_builtin(__builtin_amdgcn_exp2f)
    return __builtin_amdgcn_exp2f(x);
#else
    return exp2f(x);
#endif
}
static __device__ __forceinline__ unsigned cvt_pk_bf16(float lo, float hi) {
    unsigned r;
    asm("v_cvt_pk_bf16_f32 %0, %1, %2" : "=v"(r) : "v"(lo), "v"(hi));
    return r;
}

// ---------------- Kernel 0: wa (log2 domain) + W transpose/bf16-split ----------------
__global__ __launch_bounds__(256) void wa_kernel(const float* __restrict__ W,
                                                 const float* __restrict__ a,
                                                 float* __restrict__ wa,
                                                 unsigned short* __restrict__ wthi,
                                                 unsigned short* __restrict__ wtlo) {
    __shared__ unsigned short shi[FIN * 132];
    __shared__ unsigned short slo[FIN * 132];
    int hh = blockIdx.x;
    int t = threadIdx.x;

    const float* Ws = W + (size_t)hh * FIN * FOUT;
    for (int idx = t; idx < FIN * FOUT; idx += 256) {
        int f = idx >> 7, o = idx & 127;
        float wv = Ws[idx];
        unsigned short uh = f2bf(wv);
        shi[o * 132 + f] = uh;
        slo[o * 132 + f] = f2bf(wv - bf2f(uh));
    }

    int f = t >> 1, half = t & 1;
    const float* Wr = Ws + (size_t)f * FOUT + half * 64;
    const float* ar = a + (size_t)hh * 2 * FOUT + half * 64;
    float s1 = 0.f, s2 = 0.f;
    for (int o = 0; o < 64; o += 4) {
        float4 w4 = *(const float4*)&Wr[o];
        s1 += w4.x * ar[o] + w4.y * ar[o + 1] + w4.z * ar[o + 2] + w4.w * ar[o + 3];
        s2 += w4.x * ar[FOUT + o] + w4.y * ar[FOUT + o + 1] + w4.z * ar[FOUT + o + 2] + w4.w * ar[FOUT + o + 3];
    }
    s1 += __shfl_xor(s1, 1, 64);
    s2 += __shfl_xor(s2, 1, 64);
    if (half == 0) {
        wa[(hh * 2 + 0) * FIN + f] = s1 * LOG2E;
        wa[(hh * 2 + 1) * FIN + f] = s2 * LOG2E;
    }

    __syncthreads();
    unsigned short* dhi = wthi + (size_t)hh * FOUT * FIN;
    unsigned short* dlo = wtlo + (size_t)hh * FOUT * FIN;
    for (int idx = t; idx < FIN * FOUT; idx += 256) {
        int o = idx >> 7, ff = idx & 127;
        dhi[idx] = shi[o * 132 + ff];
        dlo[idx] = slo[o * 132 + ff];
    }
}

// ---------------- Fat prep kernel: pack (0..255) | sij (256..4351) | wh (4352..4863) -------------
// pack: each wave streams 16 CONTIGUOUS adj rows (128 KB sequential) -> ballot -> LDS ->
//       block-wide coalesced transposed writeout to jt-major adjp.
// whf layout (per b,h): chunk = (jt*4 + kt)*4 + ctq; elem (col o, row n):
//   jt=n>>6, kt=(n>>4)&3, kh=(n>>3)&1, i=n&7, ctq=o>>5; flat = (chunk*64 + kh*32 + (o&31))*8 + i
__global__ __launch_bounds__(256, 4) void prep_kernel(
    const float* __restrict__ h, const int* __restrict__ adj,
    const float* __restrict__ wa,
    const unsigned short* __restrict__ wthi, const unsigned short* __restrict__ wtlo,
    u64* __restrict__ adjp, unsigned short* __restrict__ whf,
    float* __restrict__ si, float* __restrict__ sj) {
    __shared__ u64 plds[64][33];   // [row][jt], +1 pad (writeout bank spread)

    int bid = blockIdx.x;
    int t   = threadIdx.x;

    if (bid < 256) {
        // ---------------- pack: contiguous streaming + ballot ----------------
        int wv = t >> 6, l = t & 63;
        int gb    = bid >> 5;                    // batch
        int rbase = (bid & 31) * 64 + wv * 16;   // wave's 16 rows
        const int* src = adj + ((size_t)gb * Nv + rbase) * Nv + l;
        for (int r = 0; r < 16; ++r) {
            const int* rp = src + (size_t)r * Nv;
#pragma unroll
            for (int jt8 = 0; jt8 < 32; jt8 += 8) {
                int av[8];
#pragma unroll
                for (int k = 0; k < 8; ++k) av[k] = rp[(jt8 + k) * 64];
                u64 mm[8];
#pragma unroll
                for (int k = 0; k < 8; ++k) mm[k] = __ballot(av[k] != 0);
                if (l == 0) {
#pragma unroll
                    for (int k = 0; k < 8; ++k) plds[wv * 16 + r][jt8 + k] = mm[k];
                }
            }
        }
        __syncthreads();
        int n0B = (bid & 31) * 64;
#pragma unroll
        for (int i = 0; i < 8; ++i) {
            int idx = i * 256 + t;
            int jt = idx >> 6, row = idx & 63;
            adjp[((size_t)gb * 32 + jt) * Nv + n0B + row] = plds[row][jt];
        }
    } else if (bid < 4352) {
        // ---------------- sij ----------------
        int row  = (bid - 256) * 4 + (t >> 6);
        int lane = t & 63;
        float x0 = h[(size_t)row * FIN + lane];
        float x1 = h[(size_t)row * FIN + 64 + lane];
        float s[4];
#pragma unroll
        for (int q = 0; q < 4; ++q) {
            const float* wp = wa + q * FIN;
            s[q] = x0 * wp[lane] + x1 * wp[64 + lane];
        }
#pragma unroll
        for (int m = 32; m >= 1; m >>= 1) {
#pragma unroll
            for (int q = 0; q < 4; ++q) s[q] += __shfl_xor(s[q], m, 64);
        }
        if (lane == 0) {
            int bb = row >> 11, n = row & (Nv - 1);
            si[((size_t)(bb * NH + 0)) * Nv + n] = s[0];
            sj[((size_t)(bb * NH + 0)) * Nv + n] = s[1];
            si[((size_t)(bb * NH + 1)) * Nv + n] = s[2];
            sj[((size_t)(bb * NH + 1)) * Nv + n] = s[3];
        }
    } else {
        // ---------------- wh: Wh bf16 (hi/lo split, fp32-accurate) into frag-major whf ----------
        int wb2 = bid - 4352;          // 0..511
        int bb  = wb2 & 7;
        int r2  = wb2 >> 3;
        int hh  = r2 & 1;
        int jtb = r2 >> 1;             // 64-row tile index
        int n0  = jtb * 64;

        int w = t >> 6, l = t & 63, lo16 = l & 15, grp = l >> 4;
        int o0 = w * 32;

        const unsigned short* Whi = wthi + (size_t)hh * FOUT * FIN;
        const unsigned short* Wlo = wtlo + (size_t)hh * FOUT * FIN;
        short8 ahi[2][4], alo[2][4];
#pragma unroll
        for (int ot = 0; ot < 2; ++ot)
#pragma unroll
            for (int kt = 0; kt < 4; ++kt) {
                int off = (o0 + ot * 16 + lo16) * FIN + kt * 32 + grp * 8;
                ahi[ot][kt] = *(const short8*)&Whi[off];
                alo[ot][kt] = *(const short8*)&Wlo[off];
            }

        f32x4 acc[2][4];
#pragma unroll
        for (int ot = 0; ot < 2; ++ot)
#pragma unroll
            for (int nt = 0; nt < 4; ++nt) acc[ot][nt] = (f32x4){0.f, 0.f, 0.f, 0.f};

        const float* hb = h + ((size_t)bb * Nv + n0) * FIN;
#pragma unroll
        for (int nt = 0; nt < 4; ++nt) {
#pragma unroll
            for (int kt = 0; kt < 4; ++kt) {
                const float* hp = hb + (size_t)(nt * 16 + lo16) * FIN + kt * 32 + grp * 8;
                float4 x0 = *(const float4*)hp;
                float4 x1 = *(const float4*)(hp + 4);
                float xs[8] = {x0.x, x0.y, x0.z, x0.w, x1.x, x1.y, x1.z, x1.w};
                short8 bhi, blo;
#pragma unroll
                for (int i = 0; i < 8; ++i) {
                    unsigned short uh = f2bf(xs[i]);
                    bhi[i] = (short)uh;
                    blo[i] = (short)f2bf(xs[i] - bf2f(uh));
                }
#pragma unroll
                for (int ot = 0; ot < 2; ++ot) {
                    acc[ot][nt] = __builtin_amdgcn_mfma_f32_16x16x32_bf16(ahi[ot][kt], bhi, acc[ot][nt], 0, 0, 0);
                    acc[ot][nt] = __builtin_amdgcn_mfma_f32_16x16x32_bf16(ahi[ot][kt], blo, acc[ot][nt], 0, 0, 0);
                    acc[ot][nt] = __builtin_amdgcn_mfma_f32_16x16x32_bf16(alo[ot][kt], bhi, acc[ot][nt], 0, 0, 0);
                }
            }
        }
        unsigned short* db = whf + (size_t)(bb * NH + hh) * 262144;
#pragma unroll
        for (int ot = 0; ot < 2; ++ot)
#pragma unroll
            for (int nt = 0; nt < 4; ++nt)
#pragma unroll
                for (int reg = 0; reg < 4; ++reg) {
                    int oc = ot * 16 + grp * 4 + reg;
                    db[(size_t)(((jtb * 4 + nt) * 4 + w) * 64 + (lo16 >> 3) * 32 + oc) * 8 + (lo16 & 7)] =
                        f2bf(acc[ot][nt][reg]);
                }
    }
}

// ---------------- attn: 32x32x16 MFMA, j-split x2, no online max, bitmask adj ----------------
// grid 1024: bb=bid&7 (XCD), rp=(bid>>3)&31 (64-row pair), hh=(bid>>8)&1, ch=bid>>9 (col half).
// 4 waves: jp=w&1 (j-half, 16 tiles each), rw=w>>1 (32-row group). Wave: 32 rows x 64 cols.
// A layout (32x32x16): row=l&31, k=(l>>5)*8+i. C/D: col=l&31, row=(reg&3)+8*(reg>>2)+4*(l>>5).
__global__ __launch_bounds__(256, 3) void gat_attn_kernel(
    const u64* __restrict__ adjp, const unsigned short* __restrict__ whf,
    const float* __restrict__ si, const float* __restrict__ sj,
    float* __restrict__ out) {
    int bid = blockIdx.x;
    int bb  = bid & 7;
    int r2  = bid >> 3;
    int rp  = r2 & 31;
    int hh  = (r2 >> 5) & 1;
    int ch  = r2 >> 6;

    int t = threadIdx.x, w = t >> 6, l = t & 63;
    int jp = w & 1, rw = w >> 1;
    int lo32 = l & 31, kh = l >> 5;
    int r0 = rp * 64 + rw * 32;
    int myrow = r0 + lo32;

    float sir = si[(size_t)(bb * NH + hh) * Nv + myrow];
    const u64*   adjr = adjp + (size_t)bb * 32 * Nv + myrow;
    const float* sjb  = sj + (size_t)(bb * NH + hh) * Nv;
    const unsigned short* wbp = whf + (size_t)(bb * NH + hh) * 262144 + (size_t)l * 8;

    f32x16 acc0, acc1, accL;
#pragma unroll
    for (int i = 0; i < 16; ++i) { acc0[i] = 0.f; acc1[i] = 0.f; accL[i] = 0.f; }

    const int ones_w = 0x3f803f80;
    short8 onesf = __builtin_bit_cast(short8, (i32x4){ones_w, ones_w, ones_w, ones_w});

    int jt0 = jp * 16;
    u64 mask = adjr[(size_t)jt0 * Nv];
    for (int jtl = 0; jtl < 16; ++jtl) {
        int jt = jt0 + jtl;
        int jb = jt * 64;
        const unsigned short* fb = wbp + (size_t)(jt * 16 + ch * 2) * 512;
        short8 bf[4][2];
#pragma unroll
        for (int kt = 0; kt < 4; ++kt) {
            bf[kt][0] = *(const short8*)(fb + (kt * 4 + 0) * 512);
            bf[kt][1] = *(const short8*)(fb + (kt * 4 + 1) * 512);
        }
        u64 mcur = mask;
        if (jtl < 15) mask = adjr[(size_t)(jt + 1) * Nv];

        short8 af[4];
#pragma unroll
        for (int kt = 0; kt < 4; ++kt) {
            unsigned mb = (unsigned)(mcur >> (kt * 16 + kh * 8)) & 0xFFu;
            const float* sp = &sjb[jb + kt * 16 + kh * 8];
            float4 s0 = *(const float4*)sp;
            float4 s1 = *(const float4*)(sp + 4);
            float x0 = sir + s0.x, x1 = sir + s0.y, x2 = sir + s0.z, x3 = sir + s0.w;
            float x4 = sir + s1.x, x5 = sir + s1.y, x6 = sir + s1.z, x7 = sir + s1.w;
            x0 = fmaxf(x0, 0.2f * x0); x1 = fmaxf(x1, 0.2f * x1);
            x2 = fmaxf(x2, 0.2f * x2); x3 = fmaxf(x3, 0.2f * x3);
            x4 = fmaxf(x4, 0.2f * x4); x5 = fmaxf(x5, 0.2f * x5);
            x6 = fmaxf(x6, 0.2f * x6); x7 = fmaxf(x7, 0.2f * x7);
            float p0 = fast_exp2(x0), p1 = fast_exp2(x1), p2 = fast_exp2(x2), p3 = fast_exp2(x3);
            float p4 = fast_exp2(x4), p5 = fast_exp2(x5), p6 = fast_exp2(x6), p7 = fast_exp2(x7);
            p0 = (mb & 1u)   ? p0 : 0.f;  p1 = (mb & 2u)   ? p1 : 0.f;
            p2 = (mb & 4u)   ? p2 : 0.f;  p3 = (mb & 8u)   ? p3 : 0.f;
            p4 = (mb & 16u)  ? p4 : 0.f;  p5 = (mb & 32u)  ? p5 : 0.f;
            p6 = (mb & 64u)  ? p6 : 0.f;  p7 = (mb & 128u) ? p7 : 0.f;
            unsigned w0 = cvt_pk_bf16(p0, p1), w1 = cvt_pk_bf16(p2, p3);
            unsigned w2 = cvt_pk_bf16(p4, p5), w3 = cvt_pk_bf16(p6, p7);
            af[kt] = __builtin_bit_cast(short8, (i32x4){(int)w0, (int)w1, (int)w2, (int)w3});
        }
#pragma unroll
        for (int kt = 0; kt < 4; ++kt) {
            acc0 = __builtin_amdgcn_mfma_f32_32x32x16_bf16(af[kt], bf[kt][0], acc0, 0, 0, 0);
            acc1 = __builtin_amdgcn_mfma_f32_32x32x16_bf16(af[kt], bf[kt][1], acc1, 0, 0, 0);
            accL = __builtin_amdgcn_mfma_f32_32x32x16_bf16(af[kt], onesf,    accL, 0, 0, 0);
        }
    }

    // ---- j-split combine (plain sums) + normalize + store ----
    __shared__ float red[2][64][49];
    if (jp == 1) {
#pragma unroll
        for (int i = 0; i < 16; ++i) {
            red[rw][l][i]      = acc0[i];
            red[rw][l][16 + i] = acc1[i];
            red[rw][l][32 + i] = accL[i];
        }
    }
    __syncthreads();
    if (jp == 0) {
#pragma unroll
        for (int i = 0; i < 16; ++i) {
            acc0[i] += red[rw][l][i];
            acc1[i] += red[rw][l][16 + i];
            accL[i] += red[rw][l][32 + i];
        }
#pragma unroll
        for (int reg = 0; reg < 16; ++reg) {
            int rowc = (reg & 3) + 8 * (reg >> 2) + 4 * kh;
            float linv = 1.0f / accL[reg];
            float* op = out + ((size_t)(bb * Nv + r0 + rowc)) * (NH * FOUT) + hh * FOUT + ch * 64;
            op[lo32]      = acc0[reg] * linv;
            op[32 + lo32] = acc1[reg] * linv;
        }
    }
}

extern "C" void kernel_launch(void* const* d_in, const int* in_sizes, int n_in,
                              void* d_out, int out_size, void* d_ws, size_t ws_size,
                              hipStream_t stream) {
    const float* h   = (const float*)d_in[0];
    const int*   adj = (const int*)d_in[1];
    const float* W   = (const float*)d_in[2];
    const float* a   = (const float*)d_in[3];
    float*       out = (float*)d_out;

    char* ws = (char*)d_ws;
    unsigned short* whf  = (unsigned short*)ws;                  // 8.39 MB
    u64*            adjp = (u64*)(ws + 8388608);                 // 4.19 MB
    float* si = (float*)(ws + 8388608 + 4194304);                // 128 KB
    float* sj = si + (size_t)Bv * NH * Nv;                       // 128 KB
    float* wa = sj + (size_t)Bv * NH * Nv;                       // 2 KB
    unsigned short* wthi = (unsigned short*)(wa + NH * 2 * FIN); // 64 KB
    unsigned short* wtlo = wthi + (size_t)NH * FOUT * FIN;       // 64 KB

    wa_kernel  <<<dim3(2),    dim3(256), 0, stream>>>(W, a, wa, wthi, wtlo);
    prep_kernel<<<dim3(4864), dim3(256), 0, stream>>>(h, adj, wa, wthi, wtlo, adjp, whf, si, sj);
    gat_attn_kernel<<<dim3(1024), dim3(256), 0, stream>>>(adjp, whf, si, sj, out);
}